// Round 1
// baseline (1081.680 us; speedup 1.0000x reference)
//
#include <hip/hip_runtime.h>

typedef __attribute__((ext_vector_type(8))) __bf16 bf16x8;
typedef __attribute__((ext_vector_type(4))) float f32x4;

#define MFMA16(a, b, c) __builtin_amdgcn_mfma_f32_16x16x32_bf16((a), (b), (c), 0, 0, 0)
#define LOG2E 1.4426950408889634f

constexpr int S_LEN = 2048;
constexpr int DIM   = 64;
constexpr int QT    = 16;   // q rows per block
constexpr int KT    = 64;   // k rows per tile (16 cols per wave x 4 waves)
constexpr int NBH   = 32;   // B*H

// ---------------- kernel 0: 1/max(||k_row||, eps) ----------------
__global__ void knorm_kernel(const float* __restrict__ kg, float* __restrict__ invk) {
    int gw   = (blockIdx.x * blockDim.x + threadIdx.x) >> 6;  // one wave per row
    int lane = threadIdx.x & 63;
    float x  = kg[(size_t)gw * DIM + lane];
    float ss = x * x;
#pragma unroll
    for (int off = 1; off < 64; off <<= 1) ss += __shfl_xor(ss, off);
    if (lane == 0) invk[gw] = 1.0f / fmaxf(sqrtf(ss), 1e-12f);
}

// QK^T one 16x64 sub-tile contribution for one wave (split-precision bf16 MFMA).
__device__ __forceinline__ f32x4 qk_tile(const float* __restrict__ kr, float ik,
                                         const bf16x8* aqh, const bf16x8* aql, int quad) {
    f32x4 a0 = {0.f, 0.f, 0.f, 0.f}, a1 = {0.f, 0.f, 0.f, 0.f};
#pragma unroll
    for (int ks = 0; ks < 2; ++ks) {
        const float* p = kr + ks * 32 + quad * 8;
        float4 x0 = *(const float4*)(p);
        float4 x1 = *(const float4*)(p + 4);
        float xs[8] = {x0.x, x0.y, x0.z, x0.w, x1.x, x1.y, x1.z, x1.w};
        bf16x8 bh_, bl_;
#pragma unroll
        for (int j = 0; j < 8; ++j) {
            float x = xs[j] * ik;
            __bf16 h = (__bf16)x;
            bh_[j] = h;
            bl_[j] = (__bf16)(x - (float)h);
        }
        if (ks == 0) {
            a0 = MFMA16(aqh[0], bh_, a0);
            a0 = MFMA16(aqh[0], bl_, a0);
            a0 = MFMA16(aql[0], bh_, a0);
        } else {
            a1 = MFMA16(aqh[1], bh_, a1);
            a1 = MFMA16(aqh[1], bl_, a1);
            a1 = MFMA16(aql[1], bh_, a1);
        }
    }
    return a0 + a1;
}

// ---------------- main fused attention kernel ----------------
__global__ __launch_bounds__(256, 4)
void attn_kernel(const float* __restrict__ qg, const float* __restrict__ kg,
                 const float* __restrict__ vg, const float* __restrict__ invk,
                 float* __restrict__ outg, float* __restrict__ scoreg) {
    __shared__ float vstage[KT * 65];   // stride 65: 2-way bank aliasing only (free)
    __shared__ float pstage[QT * 65];
    __shared__ float sinvk[S_LEN];
    __shared__ float sinvq[QT];
    __shared__ float sinvl[QT];
    __shared__ float redbuf[4][QT];

    const int bh   = blockIdx.y;
    const int q0   = blockIdx.x * QT;
    const int tid  = threadIdx.x;
    const int lane = tid & 63;
    const int wv   = tid >> 6;     // wave 0..3
    const int quad = lane >> 4;    // 0..3
    const int l16  = lane & 15;

    const size_t hbase = (size_t)bh * S_LEN * DIM;

    // stage per-head inverse K norms
    for (int i = tid; i < S_LEN; i += 256) sinvk[i] = invk[bh * S_LEN + i];

    // q-row inverse norms, folded with 1/temperature
    {
        int row = tid >> 4, c = tid & 15;
        const float* p = qg + hbase + (size_t)(q0 + row) * DIM;
        float ss = 0.f;
#pragma unroll
        for (int j = 0; j < 4; ++j) { float x = p[c + 16 * j]; ss += x * x; }
#pragma unroll
        for (int off = 1; off < 16; off <<= 1) ss += __shfl_xor(ss, off);
        if (c == 0) sinvq[row] = 10.0f / fmaxf(sqrtf(ss), 1e-12f);
    }
    __syncthreads();

    // Build Q A-fragments (m = l16, k = quad*8 + j), split hi/lo
    bf16x8 aqh[2], aql[2];
    {
        const float* qr = qg + hbase + (size_t)(q0 + l16) * DIM;
        float iq = sinvq[l16];
#pragma unroll
        for (int ks = 0; ks < 2; ++ks) {
            const float* p = qr + ks * 32 + quad * 8;
            float4 x0 = *(const float4*)(p);
            float4 x1 = *(const float4*)(p + 4);
            float xs[8] = {x0.x, x0.y, x0.z, x0.w, x1.x, x1.y, x1.z, x1.w};
#pragma unroll
            for (int j = 0; j < 8; ++j) {
                float x = xs[j] * iq;
                __bf16 h = (__bf16)x;
                aqh[ks][j] = h;
                aql[ks][j] = (__bf16)(x - (float)h);
            }
        }
    }

    // ---- pass 1: row sums of exp(s - 10) (no barriers in loop) ----
    float lacc[4] = {0.f, 0.f, 0.f, 0.f};
    for (int kt = 0; kt < S_LEN; kt += KT) {
        int ncol = kt + wv * 16 + l16;
        const float* kr = kg + hbase + (size_t)ncol * DIM;
        f32x4 sv = qk_tile(kr, sinvk[ncol], aqh, aql, quad);
#pragma unroll
        for (int r = 0; r < 4; ++r) lacc[r] += exp2f((sv[r] - 10.0f) * LOG2E);
    }
#pragma unroll
    for (int r = 0; r < 4; ++r) {
#pragma unroll
        for (int off = 1; off < 16; off <<= 1) lacc[r] += __shfl_xor(lacc[r], off);
    }
    if (l16 == 0) {
#pragma unroll
        for (int r = 0; r < 4; ++r) redbuf[wv][quad * 4 + r] = lacc[r];
    }
    __syncthreads();
    if (tid < QT) {
        float l = redbuf[0][tid] + redbuf[1][tid] + redbuf[2][tid] + redbuf[3][tid];
        sinvl[tid] = 1.0f / l;
    }
    __syncthreads();

    float il[4];
#pragma unroll
    for (int r = 0; r < 4; ++r) il[r] = sinvl[quad * 4 + r];

    // ---- pass 2: recompute s, write score, accumulate O = P.V ----
    f32x4 o0 = {0.f, 0.f, 0.f, 0.f}, o1 = {0.f, 0.f, 0.f, 0.f};
    float* srow = scoreg + (size_t)bh * S_LEN * S_LEN;

    for (int kt = 0; kt < S_LEN; kt += KT) {
        // cooperative V tile stage (coalesced)
        const float* vt = vg + hbase + (size_t)kt * DIM;
#pragma unroll
        for (int e = 0; e < 16; ++e) {
            int i = tid + 256 * e;
            vstage[(i >> 6) * 65 + (i & 63)] = vt[i];
        }
        int ncol = kt + wv * 16 + l16;
        const float* kr = kg + hbase + (size_t)ncol * DIM;
        f32x4 sv = qk_tile(kr, sinvk[ncol], aqh, aql, quad);
        float pv[4];
#pragma unroll
        for (int r = 0; r < 4; ++r) {
            pv[r] = exp2f((sv[r] - 10.0f) * LOG2E) * il[r];
            srow[(size_t)(q0 + quad * 4 + r) * S_LEN + ncol] = pv[r];   // C-layout store
            pstage[(quad * 4 + r) * 65 + wv * 16 + l16] = pv[r];        // C->A transpose via LDS
        }
        __syncthreads();
        // P.V: A = p (m=l16, k=quad*8+j), B = v (n=wv*16+l16, k rows of tile)
#pragma unroll
        for (int ks = 0; ks < 2; ++ks) {
            bf16x8 ph, pl, vh, vl;
#pragma unroll
            for (int j = 0; j < 8; ++j) {
                int kk = ks * 32 + quad * 8 + j;
                float pp = pstage[l16 * 65 + kk];
                __bf16 h = (__bf16)pp;
                ph[j] = h;
                pl[j] = (__bf16)(pp - (float)h);
                float vv = vstage[kk * 65 + wv * 16 + l16];
                h = (__bf16)vv;
                vh[j] = h;
                vl[j] = (__bf16)(vv - (float)h);
            }
            if (ks == 0) {
                o0 = MFMA16(ph, vh, o0);
                o0 = MFMA16(ph, vl, o0);
                o0 = MFMA16(pl, vh, o0);
            } else {
                o1 = MFMA16(ph, vh, o1);
                o1 = MFMA16(ph, vl, o1);
                o1 = MFMA16(pl, vh, o1);
            }
        }
        __syncthreads();
    }

    f32x4 o = o0 + o1;
#pragma unroll
    for (int r = 0; r < 4; ++r)
        outg[hbase + (size_t)(q0 + quad * 4 + r) * DIM + wv * 16 + l16] = o[r];
}

extern "C" void kernel_launch(void* const* d_in, const int* in_sizes, int n_in,
                              void* d_out, int out_size, void* d_ws, size_t ws_size,
                              hipStream_t stream) {
    const float* q = (const float*)d_in[0];
    const float* k = (const float*)d_in[1];
    const float* v = (const float*)d_in[2];
    float* out   = (float*)d_out;
    float* score = out + (size_t)NBH * S_LEN * DIM;
    float* invk  = (float*)d_ws;   // NBH*S_LEN floats = 256 KB

    knorm_kernel<<<dim3(NBH * S_LEN / 4), 256, 0, stream>>>(k, invk);
    attn_kernel<<<dim3(S_LEN / QT, NBH), 256, 0, stream>>>(q, k, v, invk, out, score);
}